// Round 1
// 1110.976 us; speedup vs baseline: 1.0073x; 1.0073x over previous
//
#include <hip/hip_runtime.h>
#include <hip/hip_bf16.h>

// Elman RNN: SEQ=2048, BATCH=64, IN=HID=256, fp32 in/out.
// Kernel 1: xp[b][t][n] (bf16, d_ws) = x[t]·W_ih^T + b_ih + b_hh. (unchanged)
// Kernel 2: per-batch serial scan, one workgroup per batch, W_hh in VGPRs.
//           v2: raw s_barrier + counted s_waitcnt (no vmcnt(0) drain per
//           barrier) so the next-chunk global_load_lds DMA stays in flight
//           across all 64 step barriers; ost staging removed — outputs are
//           stored directly per step (1KB contiguous, nontemporal), never
//           waited on. Arithmetic is bit-identical to v1.

typedef short          bfrag8 __attribute__((ext_vector_type(8)));  // 8 bf16 (4 VGPRs)
typedef float          f4     __attribute__((ext_vector_type(4)));
typedef unsigned short us4    __attribute__((ext_vector_type(4)));
typedef unsigned int   ui4    __attribute__((ext_vector_type(4)));

#define HPAD 264   // row pad (shorts) for the 64-row GEMM tiles
#define CH2  64    // time-steps per xp LDS chunk in the scan
#define TPB  8     // timesteps per block in xp_gemm

static __device__ __forceinline__ unsigned short f2bf(float f) {
    union { float f; unsigned u; } v; v.f = f;
    unsigned r = v.u + 0x7FFFu + ((v.u >> 16) & 1u);   // RNE truncate
    return (unsigned short)(r >> 16);
}
static __device__ __forceinline__ float bf2f(unsigned short s) {
    union { unsigned u; float f; } v; v.u = ((unsigned)s) << 16;
    return v.f;
}
static __device__ __forceinline__ void gl2lds16(const unsigned short* g, unsigned short* l) {
    __builtin_amdgcn_global_load_lds(
        (const __attribute__((address_space(1))) void*)g,
        (__attribute__((address_space(3))) void*)l, 16, 0, 0);
}

// ---------------------------------------------------------------- kernel 1
__global__ __launch_bounds__(256) void xp_gemm(
    const float* __restrict__ x, const float* __restrict__ Wih,
    const float* __restrict__ bih, const float* __restrict__ bhh,
    unsigned short* __restrict__ xp)
{
    __shared__ unsigned short xs[64 * HPAD];   // A staging (x tile, bf16)
    __shared__ unsigned short rs[64 * HPAD];   // result staging ([b][n] bf16)
    const int tid  = threadIdx.x;
    const int wave = tid >> 6;
    const int lane = tid & 63;
    const int l15  = lane & 15;
    const int quad = lane >> 4;
    const int t0   = blockIdx.x * TPB;

    // B fragments from W_ih (scattered L2 reads — done ONCE per block):
    // B[k][n] = W_ih[n][k]; lane: n=l15(+tile), k=quad*8+j
    bfrag8 Bf[4][8];
    float  bs[4];
    #pragma unroll
    for (int nt = 0; nt < 4; ++nt) {
        const int n = wave * 64 + nt * 16 + l15;
        bs[nt] = bih[n] + bhh[n];
        #pragma unroll
        for (int kt = 0; kt < 8; ++kt) {
            const float* wp = Wih + n * 256 + kt * 32 + quad * 8;
            const f4 wa = *(const f4*)wp;
            const f4 wb = *(const f4*)(wp + 4);
            union { bfrag8 v; unsigned short s[8]; } u;
            #pragma unroll
            for (int j = 0; j < 4; ++j) { u.s[j] = f2bf(wa[j]); u.s[4 + j] = f2bf(wb[j]); }
            Bf[nt][kt] = u.v;
        }
    }

    for (int tt = 0; tt < TPB; ++tt) {
        const int t = t0 + tt;

        // stage 64x256 fp32 -> bf16 LDS (coalesced dwordx4 reads)
        {
            const int rb = tid >> 6;
            const int cb = (tid & 63) * 4;
            #pragma unroll
            for (int it = 0; it < 16; ++it) {
                const int r = it * 4 + rb;
                const f4 v = *(const f4*)(x + ((long)t * 64 + r) * 256 + cb);
                us4 o;
                o[0] = f2bf(v[0]); o[1] = f2bf(v[1]);
                o[2] = f2bf(v[2]); o[3] = f2bf(v[3]);
                *(us4*)(&xs[r * HPAD + cb]) = o;
            }
        }
        __syncthreads();

        f4 acc[4][4];
        #pragma unroll
        for (int mt = 0; mt < 4; ++mt)
            #pragma unroll
            for (int nt = 0; nt < 4; ++nt)
                acc[mt][nt] = (f4){0.f, 0.f, 0.f, 0.f};

        #pragma unroll
        for (int kt = 0; kt < 8; ++kt) {
            bfrag8 Af[4];
            #pragma unroll
            for (int mt = 0; mt < 4; ++mt)
                Af[mt] = *(const bfrag8*)(&xs[(mt * 16 + l15) * HPAD + kt * 32 + quad * 8]);
            #pragma unroll
            for (int mt = 0; mt < 4; ++mt)
                #pragma unroll
                for (int nt = 0; nt < 4; ++nt)
                    acc[mt][nt] = __builtin_amdgcn_mfma_f32_16x16x32_bf16(
                        Af[mt], Bf[nt][kt], acc[mt][nt], 0, 0, 0);
        }
        __syncthreads();   // all xs reads done

        // stage results (bf16, +bias) into rs as [b][n]
        #pragma unroll
        for (int mt = 0; mt < 4; ++mt)
            #pragma unroll
            for (int r = 0; r < 4; ++r) {
                const int bb = mt * 16 + quad * 4 + r;
                #pragma unroll
                for (int nt = 0; nt < 4; ++nt)
                    rs[bb * HPAD + wave * 64 + nt * 16 + l15] = f2bf(acc[mt][nt][r] + bs[nt]);
            }
        __syncthreads();

        // coalesced 16B stores: xp[(b*2048 + t)*256 + n]
        #pragma unroll
        for (int i = 0; i < 8; ++i) {
            const int chunk = i * 256 + tid;
            const int bb  = chunk >> 5;
            const int seg = chunk & 31;
            const ui4 v = *(const ui4*)(&rs[bb * HPAD + seg * 8]);
            *(ui4*)(xp + ((long)bb * 2048 + t) * 256 + seg * 8) = v;
        }
        __syncthreads();   // store-reads of rs done before next iter's rs write
    }
}

// ---------------------------------------------------------------- kernel 2
__global__ __launch_bounds__(256, 1) void rnn_scan(
    const unsigned short* __restrict__ xp, const float* __restrict__ Whh,
    float* __restrict__ out)
{
    __shared__ unsigned short xl[2][CH2 * 256];            // xp chunks (bf16) 64 KB
    __shared__ __align__(16) unsigned short hrow[2][256];  // ping-pong h (bf16)

    const int tid  = threadIdx.x;
    const int wave = tid >> 6;
    const int lane = tid & 63;
    const int l15  = lane & 15;
    const int quad = lane >> 4;
    const int b    = blockIdx.x;

    if (tid < 32) ((ui4*)&hrow[0][0])[tid] = (ui4){0u, 0u, 0u, 0u};  // h0 = 0

    // W_hh fragments: B[k][n] = W_hh[n][k], resident in VGPRs for the whole scan
    bfrag8 Bf[4][8];
    #pragma unroll
    for (int nt = 0; nt < 4; ++nt) {
        const int n = wave * 64 + nt * 16 + l15;
        #pragma unroll
        for (int kt = 0; kt < 8; ++kt) {
            const float* wp = Whh + n * 256 + kt * 32 + quad * 8;
            const f4 wa = *(const f4*)wp;
            const f4 wb = *(const f4*)(wp + 4);
            union { bfrag8 v; unsigned short s[8]; } u;
            #pragma unroll
            for (int j = 0; j < 4; ++j) { u.s[j] = f2bf(wa[j]); u.s[4 + j] = f2bf(wb[j]); }
            Bf[nt][kt] = u.v;
        }
    }

    const unsigned short* xpb = xp + (long)b * 2048 * 256;

    // preload chunk 0 -> buf 0 (direct global->LDS DMA, lane-contiguous)
    #pragma unroll
    for (int i = 0; i < 8; ++i)
        gl2lds16(xpb + i * 2048 + tid * 8, &xl[0][i * 2048 + wave * 512]);

    const int abase = quad * 8;                       // A slice: k = quad*8 + j
    const int nsel  = wave * 64 + quad * 16 + l15;    // this lane's output column
    int p = 0;

    for (int c = 0; c < 32; ++c) {
        // issue next chunk into the other buffer; it stays IN FLIGHT across the
        // whole chunk (no vmcnt(0) at the step barriers below).
        const int cn = (c < 31) ? c + 1 : 31;
        #pragma unroll
        for (int i = 0; i < 8; ++i)
            gl2lds16(xpb + (long)cn * (CH2 * 256) + i * 2048 + tid * 8,
                     &xl[(c + 1) & 1][i * 2048 + wave * 512]);

        // counted wait: keep the 8 newest (next chunk's DMA) outstanding; all
        // older ops (this chunk's DMA, prior stores) retired. Barrier joins the
        // per-wave waits so every wave's DMA for chunk c is visible.
        asm volatile("s_waitcnt vmcnt(8)" ::: "memory");
        __builtin_amdgcn_s_barrier();
        asm volatile("" ::: "memory");

        const unsigned short* xcur = &xl[c & 1][0];
        float* outc = out + (((long)c * CH2) * 64 + b) * 256 + nsel;

        #pragma unroll 2
        for (int s = 0; s < CH2; ++s) {
            const float xv = bf2f(xcur[s * 256 + nsel]);  // issued early, used late

            // A fragments: pure broadcast of h (all M-rows identical -> all
            // D-rows are valid replicas; no zero rows needed)
            bfrag8 Af[8];
            const unsigned short* hbp = &hrow[p][0];
            #pragma unroll
            for (int kt = 0; kt < 8; ++kt)
                Af[kt] = *(const bfrag8*)(hbp + abase + kt * 32);

            f4 accA[4], accB[4];
            #pragma unroll
            for (int nt = 0; nt < 4; ++nt) {
                accA[nt] = (f4){0.f, 0.f, 0.f, 0.f};
                accB[nt] = (f4){0.f, 0.f, 0.f, 0.f};
            }
            #pragma unroll
            for (int kt = 0; kt < 4; ++kt)
                #pragma unroll
                for (int nt = 0; nt < 4; ++nt) {
                    accA[nt] = __builtin_amdgcn_mfma_f32_16x16x32_bf16(
                        Af[kt],     Bf[nt][kt],     accA[nt], 0, 0, 0);
                    accB[nt] = __builtin_amdgcn_mfma_f32_16x16x32_bf16(
                        Af[kt + 4], Bf[nt][kt + 4], accB[nt], 0, 0, 0);
                }

            // every quad holds a full replica in reg0; lane uses tile nt==quad
            const float za = (quad == 0) ? accA[0][0] : (quad == 1) ? accA[1][0]
                           : (quad == 2) ? accA[2][0] : accA[3][0];
            const float zb = (quad == 0) ? accB[0][0] : (quad == 1) ? accB[1][0]
                           : (quad == 2) ? accB[2][0] : accB[3][0];
            const float z  = za + zb + xv;

            // tanh(z) = 1 - 2/(exp2(z*2*log2e)+1); |z| small enough, no clamps
            const float e2 = exp2f(z * 2.885390082f);
            const float hv = 1.f - 2.f * __builtin_amdgcn_rcpf(e2 + 1.f);

            hrow[p ^ 1][nsel] = f2bf(hv);   // h for next step (critical path)

            // direct output store: 1KB contiguous per block-step, fire-and-
            // forget (never waited on), nontemporal to keep xp resident in L2.
            __builtin_nontemporal_store(hv, outc + (long)s * (64 * 256));

            p ^= 1;
            // raw barrier: drain LDS ops only — global stores and the next-
            // chunk DMA remain outstanding (the whole point of this version).
            asm volatile("s_waitcnt lgkmcnt(0)" ::: "memory");
            __builtin_amdgcn_s_barrier();
            asm volatile("" ::: "memory");
        }
    }
}

extern "C" void kernel_launch(void* const* d_in, const int* in_sizes, int n_in,
                              void* d_out, int out_size, void* d_ws, size_t ws_size,
                              hipStream_t stream) {
    const float* x   = (const float*)d_in[0];
    const float* Wih = (const float*)d_in[1];
    const float* Whh = (const float*)d_in[2];
    const float* bih = (const float*)d_in[3];
    const float* bhh = (const float*)d_in[4];
    float* out = (float*)d_out;
    unsigned short* xpw = (unsigned short*)d_ws;   // 2048*64*256 bf16 = 64 MiB

    if (ws_size < (size_t)2048 * 64 * 256 * 2) return;  // fail visibly, don't corrupt

    xp_gemm<<<2048 / TPB, 256, 0, stream>>>(x, Wih, bih, bhh, xpw);
    rnn_scan<<<64, 256, 0, stream>>>(xpw, Whh, out);
}